// Round 4
// baseline (181.606 us; speedup 1.0000x reference)
//
#include <hip/hip_runtime.h>
#include <math.h>

// Problem constants (fixed by setup_inputs): B=4, T=4096, D=1024, N=512
#define D_DIM 1024
#define N_BUF 512
#define ROWS 16384                 // B*T
#define TOTAL4 4194304             // B*T*D / 4 float4s
#define NB1 1024                   // K1 grid
#define NT1 512                    // K1 block (32 waves/CU at 4 blocks/CU)
#define K1_STRIDE (NB1 * NT1)      // 524288 float4
#define K1_ITERS (TOTAL4 / K1_STRIDE)   // 8

// K5 (scale) geometry
#define NT5 256
#define K5_STRIDE (NB1 * NT5)
#define K5_ITERS (TOTAL4 / K5_STRIDE)   // 16

// ws layout (float offsets)
#define PART_FLOATS (NB1 * D_DIM)       // 1,048,576 floats = 4 MB
#define M_OFF PART_FLOATS               // m[1024]
#define SIMS_OFF (M_OFF + D_DIM)        // sims[512]
#define GATE_OFF (SIMS_OFF + N_BUF)     // gate scalar
#define CNT_OFF (GATE_OFF + 1)          // unsigned counter for last-block

typedef float vfloat4 __attribute__((ext_vector_type(4)));

// gelu(x) = 0.5x(1+tanh(u)), u = sqrt(2/pi)(x + 0.044715 x^3)
// tanh(u) = 1 - 2/(e^{2u}+1)  =>  y = x * (1 - rcp(2^(a x + b x^3) + 1))
// with a = 2*sqrt(2/pi)*log2(e), b = a*0.044715 folded into one polynomial.
// x<<0: 2^u->0, rcp(1)=1 -> y=0.  x>>0: 2^u->inf, rcp->0 -> y=x.  No inf/inf.
__device__ __forceinline__ float gelu_f(float x) {
    float u = x * (2.3022081f + 0.10294318f * x * x);
    float e = __builtin_amdgcn_exp2f(u);
    return x * (1.0f - __builtin_amdgcn_rcpf(e + 1.0f));
}

// ---- K1: y = gelu(x) -> out (nontemporal), per-block column partial sums ----
// Grid stride 524288 float4 == 0 mod 256 float4-cols, so threads t and t+256
// own the same float4-column (t&255): LDS-combine the pair, then one coalesced
// 16B store per low thread into partials[block][1024]. No atomics.
__global__ __launch_bounds__(NT1, 8) void k_gelu_part(
        const float* __restrict__ x, float* __restrict__ out,
        float* __restrict__ partials) {
    __shared__ vfloat4 lds[256];
    const int t = threadIdx.x;
    const vfloat4* __restrict__ x4 = (const vfloat4*)x;
    vfloat4* __restrict__ o4 = (vfloat4*)out;

    vfloat4 acc = (vfloat4)(0.0f);
    int idx = blockIdx.x * NT1 + t;
#pragma unroll 4
    for (int k = 0; k < K1_ITERS; ++k, idx += K1_STRIDE) {
        vfloat4 v = x4[idx];
        vfloat4 y;
        y.x = gelu_f(v.x); y.y = gelu_f(v.y); y.z = gelu_f(v.z); y.w = gelu_f(v.w);
        __builtin_nontemporal_store(y, &o4[idx]);
        acc += y;
    }
    if (t >= 256) lds[t - 256] = acc;
    __syncthreads();
    if (t < 256) {
        acc += lds[t];
        ((vfloat4*)partials)[blockIdx.x * 256 + t] = acc;
    }
}

// ---- K2: reduce partials over 1024 block-rows -> m[1024] (32 blocks) ----
// Block g handles cols [g*32, g*32+32); 8 sub-groups of 32 lanes each sum
// 128 rows, LDS-combined. Also zeroes the last-block counter for K3.
__global__ __launch_bounds__(256) void k_reduce(
        const float* __restrict__ partials, float* __restrict__ m,
        unsigned* __restrict__ cnt) {
    __shared__ float red[8][32];
    const int t = threadIdx.x, sub = t >> 5, lane = t & 31;
    const int col = blockIdx.x * 32 + lane;
    float s = 0.f;
#pragma unroll 8
    for (int i = 0; i < 128; ++i) s += partials[(sub * 128 + i) * D_DIM + col];
    red[sub][lane] = s;
    __syncthreads();
    if (t < 32) {
        float tot = 0.f;
#pragma unroll
        for (int j = 0; j < 8; ++j) tot += red[j][t];
        m[blockIdx.x * 32 + t] = tot * (1.0f / (float)ROWS);
    }
    if (blockIdx.x == 0 && t == 0) *cnt = 0u;
}

__device__ __forceinline__ float block_reduce_sum256(float v, float* red) {
    const int lane = threadIdx.x & 63, w = threadIdx.x >> 6;
#pragma unroll
    for (int o = 32; o > 0; o >>= 1) v += __shfl_down(v, o);
    if (lane == 0) red[w] = v;
    __syncthreads();
    float r = red[0] + red[1] + red[2] + red[3];
    __syncthreads();
    return r;
}

// ---- K3: sims[r] per buffer row (512 blocks); the LAST block to finish
//          also computes the gate scalar (argmax + sim_g + thresholds). ----
__global__ __launch_bounds__(256) void k_simsgate(
        const float* __restrict__ m, const float* __restrict__ buf,
        const unsigned char* __restrict__ mask,
        const float* __restrict__ facil_l, const float* __restrict__ gmean,
        const float* __restrict__ facil_g, const float* __restrict__ lkl,
        const float* __restrict__ lkg,
        float* __restrict__ sims, float* __restrict__ gate_out,
        unsigned* __restrict__ cnt) {
    __shared__ float red[4];
    __shared__ bool amLast;
    __shared__ float s_best;
    __shared__ int s_bi;
    const int t = threadIdx.x, lane = t & 63, w = t >> 6;
    const int r = blockIdx.x;

    float dot = 0.f, nm2 = 0.f, nb2 = 0.f;
    for (int c = t; c < D_DIM; c += 256) {
        float mv = m[c];
        float b = buf[r * D_DIM + c];
        dot += b * mv;
        nm2 += mv * mv;
        nb2 += b * b;
    }
    dot = block_reduce_sum256(dot, red);
    nm2 = block_reduce_sum256(nm2, red);
    nb2 = block_reduce_sum256(nb2, red);
    if (t == 0) {
        float s = dot / (fmaxf(sqrtf(nm2), 1e-12f) * fmaxf(sqrtf(nb2), 1e-12f));
        sims[r] = mask[r] ? s : -1.0f;
    }

    // last-block election (release: fence before atomic)
    __threadfence();
    if (t == 0) amLast = (atomicAdd(cnt, 1u) == N_BUF - 1);
    __syncthreads();
    if (!amLast) return;
    __threadfence();  // acquire: make all sims[] stores visible

    float g = 0.f;
    for (int c = t; c < D_DIM; c += 256) g += m[c] * gmean[c];
    g = block_reduce_sum256(g, red);

    if (w == 0) {  // first-max argmax, jnp semantics
        float best = -2.0f; int bi = 0;
        for (int i = lane; i < N_BUF; i += 64) {
            float s = sims[i];
            if (s > best) { best = s; bi = i; }
        }
#pragma unroll
        for (int o = 32; o > 0; o >>= 1) {
            float ob = __shfl_down(best, o);
            int oi = __shfl_down(bi, o);
            if (ob > best || (ob == best && oi < bi)) { best = ob; bi = oi; }
        }
        if (lane == 0) { s_best = best; s_bi = bi; }
    }
    __syncthreads();

    if (t == 0) {
        float sim_l = fminf(fmaxf(s_best, 0.0f), 1.0f);
        float sim_g = fminf(fmaxf(g / fmaxf(sqrtf(nm2), 1e-12f), 0.0f), 1.0f);
        bool fire = sim_l > 0.85f;
        float fl = facil_l[s_bi] * (fire ? 2.0f : 1.0f);
        float fg = fire ? fminf(facil_g[0] * 1.5f, 16.0f) : facil_g[0];
        float kl = fminf(fmaxf(expf(lkl[0]), 0.01f), 4.0f);
        float kg = fminf(fmaxf(expf(lkg[0]), 0.01f), 4.0f);
        gate_out[0] = fminf(1.0f + kl * (fl - 1.0f) * sim_l + kg * (fg - 1.0f) * sim_g, 8.0f);
    }
}

// ---- K5: out *= gate; early-exit when gate == 1.0 (expected case:
//          facil_l==1, facil_g==1, fire=false -> gate is exactly 1.0f) ----
__global__ __launch_bounds__(NT5) void k_scale(
        float* __restrict__ out, const float* __restrict__ gate) {
    const float gv = gate[0];
    if (gv == 1.0f) return;
    vfloat4* __restrict__ o4 = (vfloat4*)out;
    int idx = blockIdx.x * NT5 + threadIdx.x;
#pragma unroll 4
    for (int k = 0; k < K5_ITERS; ++k, idx += K5_STRIDE) {
        vfloat4 v = o4[idx];
        v *= gv;
        o4[idx] = v;
    }
}

extern "C" void kernel_launch(void* const* d_in, const int* in_sizes, int n_in,
                              void* d_out, int out_size, void* d_ws, size_t ws_size,
                              hipStream_t stream) {
    const float* x        = (const float*)d_in[0];
    const float* lkl      = (const float*)d_in[1];
    const float* lkg      = (const float*)d_in[2];
    const float* buf      = (const float*)d_in[3];
    const float* facil_l  = (const float*)d_in[4];
    const float* gmean    = (const float*)d_in[5];
    const float* facil_g  = (const float*)d_in[6];
    const unsigned char* mask = (const unsigned char*)d_in[7];
    float* out = (float*)d_out;
    float* ws  = (float*)d_ws;

    float* partials = ws;
    float* m        = ws + M_OFF;
    float* sims     = ws + SIMS_OFF;
    float* gate     = ws + GATE_OFF;
    unsigned* cnt   = (unsigned*)(ws + CNT_OFF);

    k_gelu_part<<<dim3(NB1), dim3(NT1), 0, stream>>>(x, out, partials);
    k_reduce<<<dim3(32), dim3(256), 0, stream>>>(partials, m, cnt);
    k_simsgate<<<dim3(N_BUF), dim3(256), 0, stream>>>(m, buf, mask, facil_l,
                                                      gmean, facil_g, lkl, lkg,
                                                      sims, gate, cnt);
    k_scale<<<dim3(NB1), dim3(NT5), 0, stream>>>(out, gate);
}

// Round 5
// 145.889 us; speedup vs baseline: 1.2448x; 1.2448x over previous
//
#include <hip/hip_runtime.h>
#include <math.h>

// Problem constants (fixed by setup_inputs): B=4, T=4096, D=1024, N=512
#define D_DIM 1024
#define N_BUF 512
#define ROWS 16384                 // B*T
#define TOTAL4 4194304             // B*T*D / 4 float4s
#define NB1 1024                   // K1 grid
#define NT1 512                    // K1 block (8 blocks/CU x 8 waves = 32 waves/CU)
#define K1_STRIDE (NB1 * NT1)      // 524288 float4
#define K1_ITERS (TOTAL4 / K1_STRIDE)   // 8

// K5 (scale) geometry
#define NT5 256
#define K5_STRIDE (NB1 * NT5)
#define K5_ITERS (TOTAL4 / K5_STRIDE)   // 16

// ws layout (float offsets)
#define PART_FLOATS (NB1 * D_DIM)       // 1,048,576 floats = 4 MB
#define M_OFF PART_FLOATS               // m[1024]
#define SIMS_OFF (M_OFF + D_DIM)        // sims[512]
#define GATE_OFF (SIMS_OFF + N_BUF)     // gate scalar

typedef float vfloat4 __attribute__((ext_vector_type(4)));

// gelu(x) = 0.5x(1+tanh(u)), u = sqrt(2/pi)(x + 0.044715 x^3)
// tanh(u) = 1 - 2/(e^{2u}+1)  =>  y = x * (1 - rcp(2^(a x + b x^3) + 1))
// a = 2*sqrt(2/pi)*log2(e), b = a*0.044715 folded into one polynomial.
// x<<0: 2^u->0, rcp(1)=1 -> y=0.  x>>0: 2^u->inf, rcp->0 -> y=x.  No inf/inf.
__device__ __forceinline__ float gelu_f(float x) {
    float u = x * (2.3022081f + 0.10294318f * x * x);
    float e = __builtin_amdgcn_exp2f(u);
    return x * (1.0f - __builtin_amdgcn_rcpf(e + 1.0f));
}

// ---- K1: y = gelu(x) -> out (nontemporal), per-block column partial sums ----
// Grid stride 524288 float4 == 0 mod 256 float4-cols, so threads t and t+256
// own the same float4-column (t&255): LDS-combine the pair, then one coalesced
// 16B store per low thread into partials[block][1024]. No atomics, no fences.
__global__ __launch_bounds__(NT1, 8) void k_gelu_part(
        const float* __restrict__ x, float* __restrict__ out,
        float* __restrict__ partials) {
    __shared__ vfloat4 lds[256];
    const int t = threadIdx.x;
    const vfloat4* __restrict__ x4 = (const vfloat4*)x;
    vfloat4* __restrict__ o4 = (vfloat4*)out;

    vfloat4 acc = (vfloat4)(0.0f);
    int idx = blockIdx.x * NT1 + t;
#pragma unroll 4
    for (int k = 0; k < K1_ITERS; ++k, idx += K1_STRIDE) {
        vfloat4 v = x4[idx];
        vfloat4 y;
        y.x = gelu_f(v.x); y.y = gelu_f(v.y); y.z = gelu_f(v.z); y.w = gelu_f(v.w);
        __builtin_nontemporal_store(y, &o4[idx]);
        acc += y;
    }
    if (t >= 256) lds[t - 256] = acc;
    __syncthreads();
    if (t < 256) {
        acc += lds[t];
        ((vfloat4*)partials)[blockIdx.x * 256 + t] = acc;
    }
}

// ---- K2: reduce partials over 1024 block-rows -> m[1024] (32 blocks) ----
// Block g handles cols [g*32, g*32+32); 8 sub-groups of 32 lanes each sum
// 128 rows, LDS-combined.
__global__ __launch_bounds__(256) void k_reduce(
        const float* __restrict__ partials, float* __restrict__ m) {
    __shared__ float red[8][32];
    const int t = threadIdx.x, sub = t >> 5, lane = t & 31;
    const int col = blockIdx.x * 32 + lane;
    float s = 0.f;
#pragma unroll 8
    for (int i = 0; i < 128; ++i) s += partials[(sub * 128 + i) * D_DIM + col];
    red[sub][lane] = s;
    __syncthreads();
    if (t < 32) {
        float tot = 0.f;
#pragma unroll
        for (int j = 0; j < 8; ++j) tot += red[j][t];
        m[blockIdx.x * 32 + t] = tot * (1.0f / (float)ROWS);
    }
}

__device__ __forceinline__ float block_reduce_sum256(float v, float* red) {
    const int lane = threadIdx.x & 63, w = threadIdx.x >> 6;
#pragma unroll
    for (int o = 32; o > 0; o >>= 1) v += __shfl_down(v, o);
    if (lane == 0) red[w] = v;
    __syncthreads();
    float r = red[0] + red[1] + red[2] + red[3];
    __syncthreads();
    return r;
}

// ---- K3: sims[r] per buffer row (one block per row) ----
__global__ __launch_bounds__(256) void k_sims(
        const float* __restrict__ m, const float* __restrict__ buf,
        const unsigned char* __restrict__ mask, float* __restrict__ sims_out) {
    __shared__ float red[4];
    const int r = blockIdx.x;
    float dot = 0.f, nm2 = 0.f, nb2 = 0.f;
    for (int c = threadIdx.x; c < D_DIM; c += 256) {
        float mv = m[c];
        float b = buf[r * D_DIM + c];
        dot += b * mv;
        nm2 += mv * mv;
        nb2 += b * b;
    }
    dot = block_reduce_sum256(dot, red);
    nm2 = block_reduce_sum256(nm2, red);
    nb2 = block_reduce_sum256(nb2, red);
    if (threadIdx.x == 0) {
        float s = dot / (fmaxf(sqrtf(nm2), 1e-12f) * fmaxf(sqrtf(nb2), 1e-12f));
        sims_out[r] = mask[r] ? s : -1.0f;
    }
}

// ---- K4: argmax over sims, sim_g, final gate scalar (1 block) ----
__global__ __launch_bounds__(256) void k_gate(
        const float* __restrict__ m, const float* __restrict__ sims,
        const float* __restrict__ facil_l, const float* __restrict__ gmean,
        const float* __restrict__ facil_g, const float* __restrict__ lkl,
        const float* __restrict__ lkg, float* __restrict__ gate_out) {
    __shared__ float red[4];
    __shared__ float s_best;
    __shared__ int s_bi;
    const int t = threadIdx.x, lane = t & 63, w = t >> 6;

    float nm2 = 0.f, g = 0.f;
    for (int c = t; c < D_DIM; c += 256) {
        float mv = m[c];
        nm2 += mv * mv;
        g += mv * gmean[c];
    }
    nm2 = block_reduce_sum256(nm2, red);
    g = block_reduce_sum256(g, red);

    if (w == 0) {  // first-max argmax, jnp semantics
        float best = -2.0f; int bi = 0;
        for (int r = lane; r < N_BUF; r += 64) {
            float s = sims[r];
            if (s > best) { best = s; bi = r; }
        }
#pragma unroll
        for (int o = 32; o > 0; o >>= 1) {
            float ob = __shfl_down(best, o);
            int oi = __shfl_down(bi, o);
            if (ob > best || (ob == best && oi < bi)) { best = ob; bi = oi; }
        }
        if (lane == 0) { s_best = best; s_bi = bi; }
    }
    __syncthreads();

    if (t == 0) {
        float sim_l = fminf(fmaxf(s_best, 0.0f), 1.0f);
        float sim_g = fminf(fmaxf(g / fmaxf(sqrtf(nm2), 1e-12f), 0.0f), 1.0f);
        bool fire = sim_l > 0.85f;
        float fl = facil_l[s_bi] * (fire ? 2.0f : 1.0f);
        float fg = fire ? fminf(facil_g[0] * 1.5f, 16.0f) : facil_g[0];
        float kl = fminf(fmaxf(expf(lkl[0]), 0.01f), 4.0f);
        float kg = fminf(fmaxf(expf(lkg[0]), 0.01f), 4.0f);
        gate_out[0] = fminf(1.0f + kl * (fl - 1.0f) * sim_l + kg * (fg - 1.0f) * sim_g, 8.0f);
    }
}

// ---- K5: out *= gate; early-exit when gate == 1.0 (expected case:
//          facil_l==1, facil_g==1, fire=false -> gate is exactly 1.0f) ----
__global__ __launch_bounds__(NT5) void k_scale(
        float* __restrict__ out, const float* __restrict__ gate) {
    const float gv = gate[0];
    if (gv == 1.0f) return;
    vfloat4* __restrict__ o4 = (vfloat4*)out;
    int idx = blockIdx.x * NT5 + threadIdx.x;
#pragma unroll 4
    for (int k = 0; k < K5_ITERS; ++k, idx += K5_STRIDE) {
        vfloat4 v = o4[idx];
        v *= gv;
        o4[idx] = v;
    }
}

extern "C" void kernel_launch(void* const* d_in, const int* in_sizes, int n_in,
                              void* d_out, int out_size, void* d_ws, size_t ws_size,
                              hipStream_t stream) {
    const float* x        = (const float*)d_in[0];
    const float* lkl      = (const float*)d_in[1];
    const float* lkg      = (const float*)d_in[2];
    const float* buf      = (const float*)d_in[3];
    const float* facil_l  = (const float*)d_in[4];
    const float* gmean    = (const float*)d_in[5];
    const float* facil_g  = (const float*)d_in[6];
    const unsigned char* mask = (const unsigned char*)d_in[7];
    float* out = (float*)d_out;
    float* ws  = (float*)d_ws;

    float* partials = ws;
    float* m        = ws + M_OFF;
    float* sims     = ws + SIMS_OFF;
    float* gate     = ws + GATE_OFF;

    k_gelu_part<<<dim3(NB1), dim3(NT1), 0, stream>>>(x, out, partials);
    k_reduce<<<dim3(32), dim3(256), 0, stream>>>(partials, m);
    k_sims<<<dim3(N_BUF), dim3(256), 0, stream>>>(m, buf, mask, sims);
    k_gate<<<dim3(1), dim3(256), 0, stream>>>(m, sims, facil_l, gmean,
                                              facil_g, lkl, lkg, gate);
    k_scale<<<dim3(NB1), dim3(NT5), 0, stream>>>(out, gate);
}

// Round 6
// 144.464 us; speedup vs baseline: 1.2571x; 1.0099x over previous
//
#include <hip/hip_runtime.h>
#include <math.h>

// Problem constants (fixed by setup_inputs): B=4, T=4096, D=1024, N=512
#define D_DIM 1024
#define N_BUF 512
#define ROWS 16384                 // B*T
#define TOTAL4 4194304             // B*T*D / 4 float4s
#define NB1 1024                   // K1 grid
#define NT1 512                    // K1 block (8 blocks/CU x 8 waves = 32 waves/CU)
#define K1_STRIDE (NB1 * NT1)      // 524288 float4
#define K1_ITERS (TOTAL4 / K1_STRIDE)   // 8

// K5 (scale) geometry
#define NT5 256
#define K5_STRIDE (NB1 * NT5)
#define K5_ITERS (TOTAL4 / K5_STRIDE)   // 16

// ws layout (float offsets)
#define PART_FLOATS (NB1 * D_DIM)       // 1,048,576 floats = 4 MB
#define M_OFF PART_FLOATS               // m[1024]
#define SIMS_OFF (M_OFF + D_DIM)        // sims[512]
#define GATE_OFF (SIMS_OFF + N_BUF)     // gate scalar

typedef float vfloat4 __attribute__((ext_vector_type(4)));

// gelu(x) = 0.5x(1+tanh(u)), u = sqrt(2/pi)(x + 0.044715 x^3)
// tanh(u) = 1 - 2/(e^{2u}+1)  =>  y = x * (1 - rcp(2^(a x + b x^3) + 1))
// a = 2*sqrt(2/pi)*log2(e), b = a*0.044715 folded into one polynomial.
// x<<0: 2^u->0, rcp(1)=1 -> y=0.  x>>0: 2^u->inf, rcp->0 -> y=x.  No inf/inf.
__device__ __forceinline__ float gelu_f(float x) {
    float u = x * (2.3022081f + 0.10294318f * x * x);
    float e = __builtin_amdgcn_exp2f(u);
    return x * (1.0f - __builtin_amdgcn_rcpf(e + 1.0f));
}

// ---- K1: y = gelu(x) -> out (PLAIN stores: let the 256 MiB memory-side LLC
// absorb the 64 MB y-write; NT streaming to HBM was the R5 bottleneck theory),
// plus per-block column partial sums. Grid stride 524288 float4 == 0 mod 256
// float4-cols, so threads t and t+256 own the same float4-column (t&255):
// LDS-combine the pair, then one coalesced 16B store per low thread into
// partials[block][1024]. No atomics, no fences.
__global__ __launch_bounds__(NT1, 8) void k_gelu_part(
        const float* __restrict__ x, float* __restrict__ out,
        float* __restrict__ partials) {
    __shared__ vfloat4 lds[256];
    const int t = threadIdx.x;
    const vfloat4* __restrict__ x4 = (const vfloat4*)x;
    vfloat4* __restrict__ o4 = (vfloat4*)out;

    vfloat4 acc = (vfloat4)(0.0f);
    int idx = blockIdx.x * NT1 + t;
#pragma unroll 4
    for (int k = 0; k < K1_ITERS; ++k, idx += K1_STRIDE) {
        vfloat4 v = x4[idx];
        vfloat4 y;
        y.x = gelu_f(v.x); y.y = gelu_f(v.y); y.z = gelu_f(v.z); y.w = gelu_f(v.w);
        o4[idx] = y;
        acc += y;
    }
    if (t >= 256) lds[t - 256] = acc;
    __syncthreads();
    if (t < 256) {
        acc += lds[t];
        ((vfloat4*)partials)[blockIdx.x * 256 + t] = acc;
    }
}

// ---- K2: reduce partials over 1024 block-rows -> m[1024] (32 blocks) ----
// Block g handles cols [g*32, g*32+32); 8 sub-groups of 32 lanes each sum
// 128 rows, LDS-combined.
__global__ __launch_bounds__(256) void k_reduce(
        const float* __restrict__ partials, float* __restrict__ m) {
    __shared__ float red[8][32];
    const int t = threadIdx.x, sub = t >> 5, lane = t & 31;
    const int col = blockIdx.x * 32 + lane;
    float s = 0.f;
#pragma unroll 8
    for (int i = 0; i < 128; ++i) s += partials[(sub * 128 + i) * D_DIM + col];
    red[sub][lane] = s;
    __syncthreads();
    if (t < 32) {
        float tot = 0.f;
#pragma unroll
        for (int j = 0; j < 8; ++j) tot += red[j][t];
        m[blockIdx.x * 32 + t] = tot * (1.0f / (float)ROWS);
    }
}

__device__ __forceinline__ float block_reduce_sum256(float v, float* red) {
    const int lane = threadIdx.x & 63, w = threadIdx.x >> 6;
#pragma unroll
    for (int o = 32; o > 0; o >>= 1) v += __shfl_down(v, o);
    if (lane == 0) red[w] = v;
    __syncthreads();
    float r = red[0] + red[1] + red[2] + red[3];
    __syncthreads();
    return r;
}

// ---- K3: sims[r] per buffer row (one block per row) ----
__global__ __launch_bounds__(256) void k_sims(
        const float* __restrict__ m, const float* __restrict__ buf,
        const unsigned char* __restrict__ mask, float* __restrict__ sims_out) {
    __shared__ float red[4];
    const int r = blockIdx.x;
    float dot = 0.f, nm2 = 0.f, nb2 = 0.f;
    for (int c = threadIdx.x; c < D_DIM; c += 256) {
        float mv = m[c];
        float b = buf[r * D_DIM + c];
        dot += b * mv;
        nm2 += mv * mv;
        nb2 += b * b;
    }
    dot = block_reduce_sum256(dot, red);
    nm2 = block_reduce_sum256(nm2, red);
    nb2 = block_reduce_sum256(nb2, red);
    if (threadIdx.x == 0) {
        float s = dot / (fmaxf(sqrtf(nm2), 1e-12f) * fmaxf(sqrtf(nb2), 1e-12f));
        sims_out[r] = mask[r] ? s : -1.0f;
    }
}

// ---- K4: argmax over sims, sim_g, final gate scalar (1 block) ----
__global__ __launch_bounds__(256) void k_gate(
        const float* __restrict__ m, const float* __restrict__ sims,
        const float* __restrict__ facil_l, const float* __restrict__ gmean,
        const float* __restrict__ facil_g, const float* __restrict__ lkl,
        const float* __restrict__ lkg, float* __restrict__ gate_out) {
    __shared__ float red[4];
    __shared__ float s_best;
    __shared__ int s_bi;
    const int t = threadIdx.x, lane = t & 63, w = t >> 6;

    float nm2 = 0.f, g = 0.f;
    for (int c = t; c < D_DIM; c += 256) {
        float mv = m[c];
        nm2 += mv * mv;
        g += mv * gmean[c];
    }
    nm2 = block_reduce_sum256(nm2, red);
    g = block_reduce_sum256(g, red);

    if (w == 0) {  // first-max argmax, jnp semantics
        float best = -2.0f; int bi = 0;
        for (int r = lane; r < N_BUF; r += 64) {
            float s = sims[r];
            if (s > best) { best = s; bi = r; }
        }
#pragma unroll
        for (int o = 32; o > 0; o >>= 1) {
            float ob = __shfl_down(best, o);
            int oi = __shfl_down(bi, o);
            if (ob > best || (ob == best && oi < bi)) { best = ob; bi = oi; }
        }
        if (lane == 0) { s_best = best; s_bi = bi; }
    }
    __syncthreads();

    if (t == 0) {
        float sim_l = fminf(fmaxf(s_best, 0.0f), 1.0f);
        float sim_g = fminf(fmaxf(g / fmaxf(sqrtf(nm2), 1e-12f), 0.0f), 1.0f);
        bool fire = sim_l > 0.85f;
        float fl = facil_l[s_bi] * (fire ? 2.0f : 1.0f);
        float fg = fire ? fminf(facil_g[0] * 1.5f, 16.0f) : facil_g[0];
        float kl = fminf(fmaxf(expf(lkl[0]), 0.01f), 4.0f);
        float kg = fminf(fmaxf(expf(lkg[0]), 0.01f), 4.0f);
        gate_out[0] = fminf(1.0f + kl * (fl - 1.0f) * sim_l + kg * (fg - 1.0f) * sim_g, 8.0f);
    }
}

// ---- K5: out *= gate; early-exit when gate == 1.0 (expected case:
//          facil_l==1, facil_g==1, fire=false -> gate is exactly 1.0f) ----
__global__ __launch_bounds__(NT5) void k_scale(
        float* __restrict__ out, const float* __restrict__ gate) {
    const float gv = gate[0];
    if (gv == 1.0f) return;
    vfloat4* __restrict__ o4 = (vfloat4*)out;
    int idx = blockIdx.x * NT5 + threadIdx.x;
#pragma unroll 4
    for (int k = 0; k < K5_ITERS; ++k, idx += K5_STRIDE) {
        vfloat4 v = o4[idx];
        v *= gv;
        o4[idx] = v;
    }
}

extern "C" void kernel_launch(void* const* d_in, const int* in_sizes, int n_in,
                              void* d_out, int out_size, void* d_ws, size_t ws_size,
                              hipStream_t stream) {
    const float* x        = (const float*)d_in[0];
    const float* lkl      = (const float*)d_in[1];
    const float* lkg      = (const float*)d_in[2];
    const float* buf      = (const float*)d_in[3];
    const float* facil_l  = (const float*)d_in[4];
    const float* gmean    = (const float*)d_in[5];
    const float* facil_g  = (const float*)d_in[6];
    const unsigned char* mask = (const unsigned char*)d_in[7];
    float* out = (float*)d_out;
    float* ws  = (float*)d_ws;

    float* partials = ws;
    float* m        = ws + M_OFF;
    float* sims     = ws + SIMS_OFF;
    float* gate     = ws + GATE_OFF;

    k_gelu_part<<<dim3(NB1), dim3(NT1), 0, stream>>>(x, out, partials);
    k_reduce<<<dim3(32), dim3(256), 0, stream>>>(partials, m);
    k_sims<<<dim3(N_BUF), dim3(256), 0, stream>>>(m, buf, mask, sims);
    k_gate<<<dim3(1), dim3(256), 0, stream>>>(m, sims, facil_l, gmean,
                                              facil_g, lkl, lkg, gate);
    k_scale<<<dim3(NB1), dim3(NT5), 0, stream>>>(out, gate);
}

// Round 7
// 144.189 us; speedup vs baseline: 1.2595x; 1.0019x over previous
//
#include <hip/hip_runtime.h>
#include <math.h>

// Problem constants (fixed by setup_inputs): B=4, T=4096, D=1024, N=512
#define D_DIM 1024
#define N_BUF 512
#define ROWS 16384                 // B*T
#define TOTAL4 4194304             // B*T*D / 4 float4s
#define NB1 1024                   // K1 grid
#define NT1 512                    // K1 block (8 blocks/CU x 8 waves = 32 waves/CU)
#define K1_STRIDE (NB1 * NT1)      // 524288 float4
#define K1_ITERS (TOTAL4 / K1_STRIDE)   // 8

// gate+scale kernel geometry
#define NT5 256
#define K5_STRIDE (NB1 * NT5)
#define K5_ITERS (TOTAL4 / K5_STRIDE)   // 16

// ws layout (float offsets)
#define PART_FLOATS (NB1 * D_DIM)       // 1,048,576 floats = 4 MB
#define M_OFF PART_FLOATS               // m[1024]
#define SIMS_OFF (M_OFF + D_DIM)        // sims[512]

typedef float vfloat4 __attribute__((ext_vector_type(4)));

// gelu(x) = 0.5x(1+tanh(u)), u = sqrt(2/pi)(x + 0.044715 x^3)
// tanh(u) = 1 - 2/(e^{2u}+1)  =>  y = x * (1 - rcp(2^(a x + b x^3) + 1))
// a = 2*sqrt(2/pi)*log2(e), b = a*0.044715 folded into one polynomial.
// x<<0: 2^u->0, rcp(1)=1 -> y=0.  x>>0: 2^u->inf, rcp->0 -> y=x.  No inf/inf.
__device__ __forceinline__ float gelu_f(float x) {
    float u = x * (2.3022081f + 0.10294318f * x * x);
    float e = __builtin_amdgcn_exp2f(u);
    return x * (1.0f - __builtin_amdgcn_rcpf(e + 1.0f));
}

// ---- K1: y = gelu(x) -> out, plus per-block column partial sums ----
// Grid stride 524288 float4 == 0 mod 256 float4-cols, so threads t and t+256
// own the same float4-column (t&255): LDS-combine the pair, then one coalesced
// 16B store per low thread into partials[block][1024]. No atomics, no fences.
// (NT store A/B'd in R5/R6: neutral -> plain stores.)
__global__ __launch_bounds__(NT1, 8) void k_gelu_part(
        const float* __restrict__ x, float* __restrict__ out,
        float* __restrict__ partials) {
    __shared__ vfloat4 lds[256];
    const int t = threadIdx.x;
    const vfloat4* __restrict__ x4 = (const vfloat4*)x;
    vfloat4* __restrict__ o4 = (vfloat4*)out;

    vfloat4 acc = (vfloat4)(0.0f);
    int idx = blockIdx.x * NT1 + t;
#pragma unroll 4
    for (int k = 0; k < K1_ITERS; ++k, idx += K1_STRIDE) {
        vfloat4 v = x4[idx];
        vfloat4 y;
        y.x = gelu_f(v.x); y.y = gelu_f(v.y); y.z = gelu_f(v.z); y.w = gelu_f(v.w);
        o4[idx] = y;
        acc += y;
    }
    if (t >= 256) lds[t - 256] = acc;
    __syncthreads();
    if (t < 256) {
        acc += lds[t];
        ((vfloat4*)partials)[blockIdx.x * 256 + t] = acc;
    }
}

// ---- K2: reduce partials over 1024 block-rows -> m[1024] (32 blocks) ----
__global__ __launch_bounds__(256) void k_reduce(
        const float* __restrict__ partials, float* __restrict__ m) {
    __shared__ float red[8][32];
    const int t = threadIdx.x, sub = t >> 5, lane = t & 31;
    const int col = blockIdx.x * 32 + lane;
    float s = 0.f;
#pragma unroll 8
    for (int i = 0; i < 128; ++i) s += partials[(sub * 128 + i) * D_DIM + col];
    red[sub][lane] = s;
    __syncthreads();
    if (t < 32) {
        float tot = 0.f;
#pragma unroll
        for (int j = 0; j < 8; ++j) tot += red[j][t];
        m[blockIdx.x * 32 + t] = tot * (1.0f / (float)ROWS);
    }
}

__device__ __forceinline__ float block_reduce_sum256(float v, float* red) {
    const int lane = threadIdx.x & 63, w = threadIdx.x >> 6;
#pragma unroll
    for (int o = 32; o > 0; o >>= 1) v += __shfl_down(v, o);
    if (lane == 0) red[w] = v;
    __syncthreads();
    float r = red[0] + red[1] + red[2] + red[3];
    __syncthreads();
    return r;
}

// ---- K3: sims[r] per buffer row (one block per row) ----
__global__ __launch_bounds__(256) void k_sims(
        const float* __restrict__ m, const float* __restrict__ buf,
        const unsigned char* __restrict__ mask, float* __restrict__ sims_out) {
    __shared__ float red[4];
    const int r = blockIdx.x;
    float dot = 0.f, nm2 = 0.f, nb2 = 0.f;
    for (int c = threadIdx.x; c < D_DIM; c += 256) {
        float mv = m[c];
        float b = buf[r * D_DIM + c];
        dot += b * mv;
        nm2 += mv * mv;
        nb2 += b * b;
    }
    dot = block_reduce_sum256(dot, red);
    nm2 = block_reduce_sum256(nm2, red);
    nb2 = block_reduce_sum256(nb2, red);
    if (threadIdx.x == 0) {
        float s = dot / (fmaxf(sqrtf(nm2), 1e-12f) * fmaxf(sqrtf(nb2), 1e-12f));
        sims_out[r] = mask[r] ? s : -1.0f;
    }
}

// ---- K4: gate + scale fused. Every block redundantly computes the gate
// scalar from sims/m/gmean (~10 KB of LLC-hot reads, trivial ALU), then
// early-exits when gate == 1.0 (expected data path: facil_l==1, facil_g==1,
// fire=false -> multipliers are exactly 0 -> gate exactly 1.0f), else scales
// its slice of out. Removes the serializing 1-block k_gate node entirely. ----
__global__ __launch_bounds__(NT5) void k_gatescale(
        const float* __restrict__ m, const float* __restrict__ sims,
        const float* __restrict__ facil_l, const float* __restrict__ gmean,
        const float* __restrict__ facil_g, const float* __restrict__ lkl,
        const float* __restrict__ lkg, float* __restrict__ out) {
    __shared__ float red[4];
    __shared__ float s_best;
    __shared__ int s_bi;
    const int t = threadIdx.x, lane = t & 63, w = t >> 6;

    float nm2 = 0.f, g = 0.f;
    for (int c = t; c < D_DIM; c += 256) {
        float mv = m[c];
        nm2 += mv * mv;
        g += mv * gmean[c];
    }
    nm2 = block_reduce_sum256(nm2, red);   // all threads get the sum
    g = block_reduce_sum256(g, red);

    if (w == 0) {  // first-max argmax, jnp semantics
        float best = -2.0f; int bi = 0;
        for (int r = lane; r < N_BUF; r += 64) {
            float s = sims[r];
            if (s > best) { best = s; bi = r; }
        }
#pragma unroll
        for (int o = 32; o > 0; o >>= 1) {
            float ob = __shfl_down(best, o);
            int oi = __shfl_down(bi, o);
            if (ob > best || (ob == best && oi < bi)) { best = ob; bi = oi; }
        }
        if (lane == 0) { s_best = best; s_bi = bi; }
    }
    __syncthreads();

    float sim_l = fminf(fmaxf(s_best, 0.0f), 1.0f);
    float sim_g = fminf(fmaxf(g / fmaxf(sqrtf(nm2), 1e-12f), 0.0f), 1.0f);
    bool fire = sim_l > 0.85f;
    float fl = facil_l[s_bi] * (fire ? 2.0f : 1.0f);
    float fg = fire ? fminf(facil_g[0] * 1.5f, 16.0f) : facil_g[0];
    float kl = fminf(fmaxf(expf(lkl[0]), 0.01f), 4.0f);
    float kg = fminf(fmaxf(expf(lkg[0]), 0.01f), 4.0f);
    float gate = fminf(1.0f + kl * (fl - 1.0f) * sim_l + kg * (fg - 1.0f) * sim_g, 8.0f);

    if (gate == 1.0f) return;

    vfloat4* __restrict__ o4 = (vfloat4*)out;
    int idx = blockIdx.x * NT5 + t;
#pragma unroll 4
    for (int k = 0; k < K5_ITERS; ++k, idx += K5_STRIDE) {
        vfloat4 v = o4[idx];
        v *= gate;
        o4[idx] = v;
    }
}

extern "C" void kernel_launch(void* const* d_in, const int* in_sizes, int n_in,
                              void* d_out, int out_size, void* d_ws, size_t ws_size,
                              hipStream_t stream) {
    const float* x        = (const float*)d_in[0];
    const float* lkl      = (const float*)d_in[1];
    const float* lkg      = (const float*)d_in[2];
    const float* buf      = (const float*)d_in[3];
    const float* facil_l  = (const float*)d_in[4];
    const float* gmean    = (const float*)d_in[5];
    const float* facil_g  = (const float*)d_in[6];
    const unsigned char* mask = (const unsigned char*)d_in[7];
    float* out = (float*)d_out;
    float* ws  = (float*)d_ws;

    float* partials = ws;
    float* m        = ws + M_OFF;
    float* sims     = ws + SIMS_OFF;

    k_gelu_part<<<dim3(NB1), dim3(NT1), 0, stream>>>(x, out, partials);
    k_reduce<<<dim3(32), dim3(256), 0, stream>>>(partials, m);
    k_sims<<<dim3(N_BUF), dim3(256), 0, stream>>>(m, buf, mask, sims);
    k_gatescale<<<dim3(NB1), dim3(NT5), 0, stream>>>(m, sims, facil_l, gmean,
                                                     facil_g, lkl, lkg, out);
}